// Round 1
// baseline (532.295 us; speedup 1.0000x reference)
//
#include <hip/hip_runtime.h>
#include <math.h>

#define HID 128
#define NSTEPS 64
#define SLEN 65
#define THREADS 512
#define ROWS 128
#define ASTRIDE 136   // 128 + 8 f16 pad (16B) -> bank-rotating rows, 16B aligned
#define FSTRIDE 40    // 32 + 8 f16 pad

typedef _Float16 half8 __attribute__((ext_vector_type(8)));
typedef float floatx4 __attribute__((ext_vector_type(4)));

// LDS plan (dynamic, 80640 B):
//   bufA  [128][136] f16  : h0 / h1 / h2 lineage (A-operand + residual source)
//   bufB  [128][136] f16  : u / v (block-inner activations)
//   featb [128][40]  f16  : K=32 zero-padded feature rows (A-operand of G0)
//   WfS   [128]      f16  : final projection vector
//   deltabuf [128]   f32  : per-row delta carry between steps
__global__ __launch_bounds__(THREADS, 2)
void hedger(const float* __restrict__ S,
            const float* __restrict__ W0,  const float* __restrict__ b0,
            const float* __restrict__ rW1, const float* __restrict__ rb1,
            const float* __restrict__ rW2, const float* __restrict__ rb2,
            const float* __restrict__ sW1, const float* __restrict__ sb1,
            const float* __restrict__ sW2, const float* __restrict__ sb2,
            const float* __restrict__ Wf,  const float* __restrict__ bfp,
            float* __restrict__ out)
{
  extern __shared__ char smem[];
  _Float16* bufA  = (_Float16*)smem;              // 17408 halfs
  _Float16* bufB  = bufA + ROWS * ASTRIDE;        // 17408 halfs
  _Float16* featb = bufB + ROWS * ASTRIDE;        // 5120 halfs
  _Float16* WfS   = featb + ROWS * FSTRIDE;       // 128 halfs
  float* deltabuf = (float*)(WfS + HID);          // 128 floats

  const int tid  = threadIdx.x;
  const int wave = tid >> 6;
  const int lane = tid & 63;
  const int l15  = lane & 15;
  const int quad = lane >> 4;
  const int m_base = (wave >> 2) * 64;  // 2 M-blocks of 64
  const int n_base = (wave & 3) * 32;   // 4 N-blocks of 32
  const int r0 = blockIdx.x * ROWS;

  // ---- persistent B fragments: wave's 32-col slice of all 4 hidden matrices.
  // B-frag layout for 16x16x32: n = lane&15, k = quad*8 + j.
  half8 wfrag[4][4][2];  // [matrix][kIter][nTile]
  {
    const float* Wm[4] = {rW1, rW2, sW1, sW2};
#pragma unroll
    for (int m = 0; m < 4; ++m)
#pragma unroll
      for (int kq = 0; kq < 4; ++kq)
#pragma unroll
        for (int nt = 0; nt < 2; ++nt) {
          const int n  = n_base + nt * 16 + l15;
          const int kb = kq * 32 + quad * 8;
          half8 f;
#pragma unroll
          for (int j = 0; j < 8; ++j)
            f[j] = (_Float16)Wm[m][(kb + j) * HID + n];
          wfrag[m][kq][nt] = f;
        }
  }
  // W0 (8x128) as a K=32 zero-padded B operand: only quad 0 (k<8) is real.
  half8 w0frag[2];
#pragma unroll
  for (int nt = 0; nt < 2; ++nt) {
    const int n = n_base + nt * 16 + l15;
    half8 f;
#pragma unroll
    for (int j = 0; j < 8; ++j) {
      const int k = quad * 8 + j;
      f[j] = (k < 8) ? (_Float16)W0[k * HID + n] : (_Float16)0.f;
    }
    w0frag[nt] = f;
  }
  // biases for this wave's columns (C-layout col = n_base + nt*16 + lane&15)
  float b0r[2], rb1r[2], rb2r[2], sb1r[2], sb2r[2];
#pragma unroll
  for (int nt = 0; nt < 2; ++nt) {
    const int n = n_base + nt * 16 + l15;
    b0r[nt] = b0[n]; rb1r[nt] = rb1[n]; rb2r[nt] = rb2[n];
    sb1r[nt] = sb1[n]; sb2r[nt] = sb2[n];
  }
  const float bfv = bfp[0];

  // LDS init: zero feature pad (cols 8..31 stay zero forever), Wf, delta=0
  for (int i = tid; i < ROWS * FSTRIDE; i += THREADS) featb[i] = (_Float16)0.f;
  if (tid < HID)  WfS[tid] = (_Float16)Wf[tid];
  if (tid < ROWS) deltabuf[tid] = 0.f;

  // per-row feature state (threads 0..127 each own one row)
  float lm_prev = 0.f, cum_x = 0.f, qv = 0.f;
  const float* Srow = S + (size_t)(r0 + (tid & 127)) * SLEN;

  floatx4 acc[4][2];

#define ZERO_ACC() do { \
  _Pragma("unroll") for (int mt = 0; mt < 4; ++mt) \
  _Pragma("unroll") for (int nt = 0; nt < 2; ++nt) { \
    floatx4 z = {0.f, 0.f, 0.f, 0.f}; acc[mt][nt] = z; } } while (0)

#define GEMM128(SRC, MI) do { \
  _Pragma("unroll") for (int kq = 0; kq < 4; ++kq) { \
    half8 afr[4]; \
    _Pragma("unroll") for (int mt = 0; mt < 4; ++mt) \
      afr[mt] = *(const half8*)&SRC[(m_base + mt * 16 + l15) * ASTRIDE + kq * 32 + quad * 8]; \
    _Pragma("unroll") for (int mt = 0; mt < 4; ++mt) \
    _Pragma("unroll") for (int nt = 0; nt < 2; ++nt) \
      acc[mt][nt] = __builtin_amdgcn_mfma_f32_16x16x32_f16( \
          afr[mt], wfrag[MI][kq][nt], acc[mt][nt], 0, 0, 0); \
  } } while (0)

#define EPI_LRELU(BR, DST) do { \
  _Pragma("unroll") for (int mt = 0; mt < 4; ++mt) \
  _Pragma("unroll") for (int nt = 0; nt < 2; ++nt) \
  _Pragma("unroll") for (int r = 0; r < 4; ++r) { \
    const int row = m_base + mt * 16 + quad * 4 + r; \
    const int col = n_base + nt * 16 + l15; \
    float v = acc[mt][nt][r] + BR[nt]; \
    v = v > 0.f ? v : 0.2f * v; \
    DST[row * ASTRIDE + col] = (_Float16)v; \
  } } while (0)

// residual: v = acc + bias + RESBUF[cell]; each cell RMW'd only by its owner lane
#define EPI_RES(BR, RESDST) do { \
  _Pragma("unroll") for (int mt = 0; mt < 4; ++mt) \
  _Pragma("unroll") for (int nt = 0; nt < 2; ++nt) \
  _Pragma("unroll") for (int r = 0; r < 4; ++r) { \
    const int row = m_base + mt * 16 + quad * 4 + r; \
    const int col = n_base + nt * 16 + l15; \
    float v = acc[mt][nt][r] + BR[nt] + (float)RESDST[row * ASTRIDE + col]; \
    RESDST[row * ASTRIDE + col] = (_Float16)v; \
  } } while (0)

#pragma unroll 1
  for (int k = 0; k < NSTEPS; ++k) {
    __syncthreads();  // deltabuf ready; prior-step bufA readers done
    if (tid < ROWS) {
      const float lm = logf(Srow[k] * 0.01f);  // log(S/S0), S0=100
      if (k > 0) { const float r = lm - lm_prev; qv += r * r; }
      lm_prev = lm;
      cum_x += lm;
      const float tT = (float)k * (1.f / 64.f);
      _Float16* fr = &featb[tid * FSTRIDE];
      fr[0] = (_Float16)lm;                              // x
      fr[1] = (_Float16)(1.f - tT);                      // tau
      fr[2] = (_Float16)0.235f;                          // sqrt(XI0)
      fr[3] = (_Float16)deltabuf[tid];                   // delta_prev
      fr[4] = (_Float16)(cum_x / (float)(k + 1));        // run_mean
      fr[5] = (_Float16)qv;                              // qv
      fr[6] = (_Float16)(1.9f * sqrtf(qv + 1e-12f));     // eta*sqrt(qv+eps)
      fr[7] = (_Float16)tT;                              // t/T
    }
    __syncthreads();

    // G0: h0 = lrelu(featPad @ W0pad + b0)   (single K=32 iter)
    ZERO_ACC();
    {
      half8 afr[4];
#pragma unroll
      for (int mt = 0; mt < 4; ++mt)
        afr[mt] = *(const half8*)&featb[(m_base + mt * 16 + l15) * FSTRIDE + quad * 8];
#pragma unroll
      for (int mt = 0; mt < 4; ++mt)
#pragma unroll
        for (int nt = 0; nt < 2; ++nt)
          acc[mt][nt] = __builtin_amdgcn_mfma_f32_16x16x32_f16(
              afr[mt], w0frag[nt], acc[mt][nt], 0, 0, 0);
    }
    EPI_LRELU(b0r, bufA);
    __syncthreads();

    ZERO_ACC(); GEMM128(bufA, 0); EPI_LRELU(rb1r, bufB);   // u = lrelu(h0@rW1+rb1)
    __syncthreads();
    ZERO_ACC(); GEMM128(bufB, 1); EPI_RES(rb2r, bufA);     // h1 = h0 + u@rW2+rb2
    __syncthreads();
    ZERO_ACC(); GEMM128(bufA, 2); EPI_LRELU(sb1r, bufB);   // v = lrelu(h1@sW1+sb1)
    __syncthreads();
    ZERO_ACC(); GEMM128(bufB, 3); EPI_RES(sb2r, bufA);     // h2 = h1 + v@sW2+sb2
    __syncthreads();

    // final: delta = sigmoid(h2 @ Wf + bf); wave covers 16 rows, quads split K
    {
      const int row = wave * 16 + l15;
      const _Float16* hr = &bufA[row * ASTRIDE + quad * 32];
      const _Float16* wr = &WfS[quad * 32];
      float s = 0.f;
#pragma unroll
      for (int u = 0; u < 4; ++u) {
        const half8 h = *(const half8*)&hr[u * 8];
        const half8 w = *(const half8*)&wr[u * 8];
#pragma unroll
        for (int j = 0; j < 8; ++j) s += (float)h[j] * (float)w[j];
      }
      s += __shfl_xor(s, 16);
      s += __shfl_xor(s, 32);
      const float d = 1.f / (1.f + expf(-(s + bfv)));
      if (quad == 0) {
        deltabuf[row] = d;
        out[(size_t)(r0 + row) * NSTEPS + k] = d;
      }
    }
  }
#undef ZERO_ACC
#undef GEMM128
#undef EPI_LRELU
#undef EPI_RES
}

extern "C" void kernel_launch(void* const* d_in, const int* in_sizes, int n_in,
                              void* d_out, int out_size, void* d_ws, size_t ws_size,
                              hipStream_t stream) {
  const float* S   = (const float*)d_in[0];
  const float* W0  = (const float*)d_in[1];
  const float* b0  = (const float*)d_in[2];
  const float* rW1 = (const float*)d_in[3];
  const float* rb1 = (const float*)d_in[4];
  const float* rW2 = (const float*)d_in[5];
  const float* rb2 = (const float*)d_in[6];
  const float* sW1 = (const float*)d_in[7];
  const float* sb1 = (const float*)d_in[8];
  const float* sW2 = (const float*)d_in[9];
  const float* sb2 = (const float*)d_in[10];
  const float* Wf  = (const float*)d_in[11];
  const float* bf  = (const float*)d_in[12];
  float* out = (float*)d_out;

  const int B = out_size / NSTEPS;        // 32768
  const int nblocks = B / ROWS;           // 256 WGs = 1 per CU
  const int shmem = 80640;                // > 64KB -> needs the opt-in attribute

  hipFuncSetAttribute(reinterpret_cast<const void*>(hedger),
                      hipFuncAttributeMaxDynamicSharedMemorySize, shmem);
  hedger<<<nblocks, THREADS, shmem, stream>>>(
      S, W0, b0, rW1, rb1, rW2, rb2, sW1, sb1, sW2, sb2, Wf, bf, out);
}

// Round 2
// 500.766 us; speedup vs baseline: 1.0630x; 1.0630x over previous
//
#include <hip/hip_runtime.h>
#include <math.h>

#define HID 128
#define NSTEPS 64
#define SLEN 65
#define THREADS 256
#define ROWS 64
#define ASTRIDE 136   // 128 + 8 f16 pad (16B) -> bank-rotating rows, 16B aligned
#define FSTRIDE 40    // 32 + 8 f16 pad

typedef _Float16 half8 __attribute__((ext_vector_type(8)));
typedef float floatx4 __attribute__((ext_vector_type(4)));

// 2 WGs/CU (grid=512, 41KB LDS each). Each WG: 64 rows, 4 waves.
// Wave partition per GEMM: all 64 M-rows (4 mt), 32 N-cols (2 nt) -> wfrag=128 VGPR,
// A-read redundancy x4 (register-constrained minimum).
__global__ __launch_bounds__(THREADS, 2)
void hedger(const float* __restrict__ S,
            const float* __restrict__ W0,  const float* __restrict__ b0,
            const float* __restrict__ rW1, const float* __restrict__ rb1,
            const float* __restrict__ rW2, const float* __restrict__ rb2,
            const float* __restrict__ sW1, const float* __restrict__ sb1,
            const float* __restrict__ sW2, const float* __restrict__ sb2,
            const float* __restrict__ Wf,  const float* __restrict__ bfp,
            float* __restrict__ out)
{
  __shared__ _Float16 bufA[ROWS * ASTRIDE];
  __shared__ _Float16 bufB[ROWS * ASTRIDE];
  __shared__ _Float16 featb[ROWS * FSTRIDE];
  __shared__ _Float16 WfS[HID];
  __shared__ float deltabuf[ROWS];

  const int tid  = threadIdx.x;
  const int wave = tid >> 6;            // 0..3
  const int lane = tid & 63;
  const int l15  = lane & 15;
  const int quad = lane >> 4;
  const int n_base = wave * 32;         // wave's 32-col N slice
  const int r0 = blockIdx.x * ROWS;

  // ---- persistent B fragments: wave's 32-col slice of all 4 hidden matrices.
  // B-frag layout for 16x16x32: n = lane&15, k = quad*8 + j.
  half8 wfrag[4][4][2];  // [matrix][kIter][nTile]
  {
    const float* Wm[4] = {rW1, rW2, sW1, sW2};
#pragma unroll
    for (int m = 0; m < 4; ++m)
#pragma unroll
      for (int kq = 0; kq < 4; ++kq)
#pragma unroll
        for (int nt = 0; nt < 2; ++nt) {
          const int n  = n_base + nt * 16 + l15;
          const int kb = kq * 32 + quad * 8;
          half8 f;
#pragma unroll
          for (int j = 0; j < 8; ++j)
            f[j] = (_Float16)Wm[m][(kb + j) * HID + n];
          wfrag[m][kq][nt] = f;
        }
  }
  // W0 (8x128) as a K=32 zero-padded B operand: only quad 0 (k<8) is real.
  half8 w0frag[2];
#pragma unroll
  for (int nt = 0; nt < 2; ++nt) {
    const int n = n_base + nt * 16 + l15;
    half8 f;
#pragma unroll
    for (int j = 0; j < 8; ++j) {
      const int k = quad * 8 + j;
      f[j] = (k < 8) ? (_Float16)W0[k * HID + n] : (_Float16)0.f;
    }
    w0frag[nt] = f;
  }
  // biases for this wave's columns (C-layout col = n_base + nt*16 + lane&15)
  float b0r[2], rb1r[2], rb2r[2], sb1r[2], sb2r[2];
#pragma unroll
  for (int nt = 0; nt < 2; ++nt) {
    const int n = n_base + nt * 16 + l15;
    b0r[nt] = b0[n]; rb1r[nt] = rb1[n]; rb2r[nt] = rb2[n];
    sb1r[nt] = sb1[n]; sb2r[nt] = sb2[n];
  }
  const float bfv = bfp[0];

  // LDS init: zero feature pad (cols 8..31 stay zero forever), Wf, delta=0
  for (int i = tid; i < ROWS * FSTRIDE; i += THREADS) featb[i] = (_Float16)0.f;
  if (tid < HID)  WfS[tid] = (_Float16)Wf[tid];
  if (tid < ROWS) deltabuf[tid] = 0.f;

  // per-row feature state (threads 0..63 each own one row)
  float lm_prev = 0.f, cum_x = 0.f, qv = 0.f;
  const float* Srow = S + (size_t)(r0 + (tid & (ROWS - 1))) * SLEN;

  floatx4 acc[4][2];

// acc init = bias (fold the epilogue bias add)
#define INIT_BIAS(BR) do { \
  _Pragma("unroll") for (int mt = 0; mt < 4; ++mt) \
  _Pragma("unroll") for (int nt = 0; nt < 2; ++nt) { \
    floatx4 z = {BR[nt], BR[nt], BR[nt], BR[nt]}; acc[mt][nt] = z; } } while (0)

// acc init = bias + residual (read h-prev from RESBUF ahead of the MFMA phase)
#define INIT_BIAS_RES(BR, RESBUF) do { \
  _Pragma("unroll") for (int mt = 0; mt < 4; ++mt) \
  _Pragma("unroll") for (int nt = 0; nt < 2; ++nt) \
  _Pragma("unroll") for (int r = 0; r < 4; ++r) { \
    const int row = mt * 16 + quad * 4 + r; \
    const int col = n_base + nt * 16 + l15; \
    acc[mt][nt][r] = BR[nt] + (float)RESBUF[row * ASTRIDE + col]; \
  } } while (0)

#define GEMM128(SRC, MI) do { \
  _Pragma("unroll") for (int kq = 0; kq < 4; ++kq) { \
    half8 afr[4]; \
    _Pragma("unroll") for (int mt = 0; mt < 4; ++mt) \
      afr[mt] = *(const half8*)&SRC[(mt * 16 + l15) * ASTRIDE + kq * 32 + quad * 8]; \
    _Pragma("unroll") for (int mt = 0; mt < 4; ++mt) \
    _Pragma("unroll") for (int nt = 0; nt < 2; ++nt) \
      acc[mt][nt] = __builtin_amdgcn_mfma_f32_16x16x32_f16( \
          afr[mt], wfrag[MI][kq][nt], acc[mt][nt], 0, 0, 0); \
  } } while (0)

// lrelu(v) = max(v, 0.2v) ; store f16
#define EPI_LRELU(DST) do { \
  _Pragma("unroll") for (int mt = 0; mt < 4; ++mt) \
  _Pragma("unroll") for (int nt = 0; nt < 2; ++nt) \
  _Pragma("unroll") for (int r = 0; r < 4; ++r) { \
    const int row = mt * 16 + quad * 4 + r; \
    const int col = n_base + nt * 16 + l15; \
    const float v = acc[mt][nt][r]; \
    DST[row * ASTRIDE + col] = (_Float16)fmaxf(v, 0.2f * v); \
  } } while (0)

// plain store (bias+residual already folded into acc)
#define EPI_STORE(DST) do { \
  _Pragma("unroll") for (int mt = 0; mt < 4; ++mt) \
  _Pragma("unroll") for (int nt = 0; nt < 2; ++nt) \
  _Pragma("unroll") for (int r = 0; r < 4; ++r) { \
    const int row = mt * 16 + quad * 4 + r; \
    const int col = n_base + nt * 16 + l15; \
    DST[row * ASTRIDE + col] = (_Float16)acc[mt][nt][r]; \
  } } while (0)

#pragma unroll 1
  for (int k = 0; k < NSTEPS; ++k) {
    __syncthreads();  // deltabuf ready; prior-step bufA readers done
    if (tid < ROWS) {
      const float lm = logf(Srow[k] * 0.01f);  // log(S/S0), S0=100
      if (k > 0) { const float r = lm - lm_prev; qv += r * r; }
      lm_prev = lm;
      cum_x += lm;
      const float tT = (float)k * (1.f / 64.f);
      _Float16* fr = &featb[tid * FSTRIDE];
      fr[0] = (_Float16)lm;                              // x
      fr[1] = (_Float16)(1.f - tT);                      // tau
      fr[2] = (_Float16)0.235f;                          // sqrt(XI0)
      fr[3] = (_Float16)deltabuf[tid];                   // delta_prev
      fr[4] = (_Float16)(cum_x / (float)(k + 1));        // run_mean
      fr[5] = (_Float16)qv;                              // qv
      fr[6] = (_Float16)(1.9f * sqrtf(qv + 1e-12f));     // eta*sqrt(qv+eps)
      fr[7] = (_Float16)tT;                              // t/T
    }
    __syncthreads();

    // G0: h0 = lrelu(featPad @ W0pad + b0)   (single K=32 iter)
    INIT_BIAS(b0r);
    {
      half8 afr[4];
#pragma unroll
      for (int mt = 0; mt < 4; ++mt)
        afr[mt] = *(const half8*)&featb[(mt * 16 + l15) * FSTRIDE + quad * 8];
#pragma unroll
      for (int mt = 0; mt < 4; ++mt)
#pragma unroll
        for (int nt = 0; nt < 2; ++nt)
          acc[mt][nt] = __builtin_amdgcn_mfma_f32_16x16x32_f16(
              afr[mt], w0frag[nt], acc[mt][nt], 0, 0, 0);
    }
    EPI_LRELU(bufA);
    __syncthreads();

    INIT_BIAS(rb1r);            GEMM128(bufA, 0); EPI_LRELU(bufB);  // u = lrelu(h0@rW1+rb1)
    __syncthreads();
    INIT_BIAS_RES(rb2r, bufA);  GEMM128(bufB, 1); EPI_STORE(bufA);  // h1 = h0 + u@rW2+rb2
    __syncthreads();
    INIT_BIAS(sb1r);            GEMM128(bufA, 2); EPI_LRELU(bufB);  // v = lrelu(h1@sW1+sb1)
    __syncthreads();
    INIT_BIAS_RES(sb2r, bufA);  GEMM128(bufB, 3); EPI_STORE(bufA);  // h2 = h1 + v@sW2+sb2
    __syncthreads();

    // final: delta = sigmoid(h2 @ Wf + bf); each wave covers 16 rows, quads split K
    {
      const int row = wave * 16 + l15;
      const _Float16* hr = &bufA[row * ASTRIDE + quad * 32];
      const _Float16* wr = &WfS[quad * 32];
      float s = 0.f;
#pragma unroll
      for (int u = 0; u < 4; ++u) {
        const half8 h = *(const half8*)&hr[u * 8];
        const half8 w = *(const half8*)&wr[u * 8];
#pragma unroll
        for (int j = 0; j < 8; ++j) s += (float)h[j] * (float)w[j];
      }
      s += __shfl_xor(s, 16);
      s += __shfl_xor(s, 32);
      const float d = 1.f / (1.f + expf(-(s + bfv)));
      if (quad == 0) {
        deltabuf[row] = d;
        out[(size_t)(r0 + row) * NSTEPS + k] = d;
      }
    }
  }
#undef INIT_BIAS
#undef INIT_BIAS_RES
#undef GEMM128
#undef EPI_LRELU
#undef EPI_STORE
}

extern "C" void kernel_launch(void* const* d_in, const int* in_sizes, int n_in,
                              void* d_out, int out_size, void* d_ws, size_t ws_size,
                              hipStream_t stream) {
  const float* S   = (const float*)d_in[0];
  const float* W0  = (const float*)d_in[1];
  const float* b0  = (const float*)d_in[2];
  const float* rW1 = (const float*)d_in[3];
  const float* rb1 = (const float*)d_in[4];
  const float* rW2 = (const float*)d_in[5];
  const float* rb2 = (const float*)d_in[6];
  const float* sW1 = (const float*)d_in[7];
  const float* sb1 = (const float*)d_in[8];
  const float* sW2 = (const float*)d_in[9];
  const float* sb2 = (const float*)d_in[10];
  const float* Wf  = (const float*)d_in[11];
  const float* bf  = (const float*)d_in[12];
  float* out = (float*)d_out;

  const int B = out_size / NSTEPS;        // 32768
  const int nblocks = B / ROWS;           // 512 WGs -> 2 per CU
  hedger<<<nblocks, THREADS, 0, stream>>>(
      S, W0, b0, rW1, rb1, rW2, rb2, sW1, sb1, sW2, sb2, Wf, bf, out);
}